// Round 15
// baseline (151.262 us; speedup 1.0000x reference)
//
#include <hip/hip_runtime.h>
#include <cstdint>
#include <cstddef>

#define BB 2
#define CC 256
#define NN 16
#define LL 4096
#define NCH 128
#define CLEN 32
#define LOG2E 1.4426950408889634f

typedef __attribute__((ext_vector_type(8))) short short8;
typedef __attribute__((ext_vector_type(4))) float f32x4;

__device__ __forceinline__ float softplus_f(float z) {
    return fmaxf(z, 0.f) + log1pf(expf(-fabsf(z)));
}

__device__ __forceinline__ uint32_t pack_bf2(float d, float u) {
    uint32_t lo = (__float_as_uint(d) + 0x8000u) >> 16;
    uint32_t hh = (__float_as_uint(u) + 0x8000u) & 0xffff0000u;
    return hh | lo;
}

__device__ __forceinline__ short bf16r(float f) {
    return (short)((__float_as_uint(f) + 0x8000u) >> 16);
}

// ---------------- K1 (MFMA): Z = X@Wd via bf16 matrix cores (R14 form) ------
__global__ __launch_bounds__(256) void k1_mfma(
    const float* __restrict__ feat, const float* __restrict__ Wd,
    const float* __restrict__ bd, const float* __restrict__ WB,
    const float* __restrict__ WC, uint32_t* __restrict__ du,
    float* __restrict__ Bm, float* __restrict__ Cm)
{
    int blk = blockIdx.x;               // b*512 + lt*4 + ct
    int b  = blk >> 9;
    int lt = (blk >> 2) & 127;
    int ct = blk & 3;
    int l0 = lt * 32, c0 = ct * 64;
    const float* fbase = feat + (size_t)b * CC * LL;
    int lane = threadIdx.x & 63;
    int wq   = threadIdx.x >> 6;
    int m    = lane & 15;
    int quad = lane >> 4;
    int m0   = (wq & 1) * 16;
    int n0   = (wq >> 1) * 32;
    bool doBC = (ct == 0);
    const float* wBC = (wq >> 1) ? WC : WB;

    f32x4 acc0 = {0.f, 0.f, 0.f, 0.f};
    f32x4 acc1 = {0.f, 0.f, 0.f, 0.f};
    f32x4 accB = {0.f, 0.f, 0.f, 0.f};

    const float* aptr  = fbase + (size_t)(quad * 8) * LL + (l0 + m0 + m);
    const float* b0ptr = Wd    + (size_t)(quad * 8) * CC + (c0 + n0 + m);
    const float* b1ptr = b0ptr + 16;
    const float* bbptr = wBC   + (size_t)(quad * 8) * NN + m;

    for (int ks = 0; ks < 8; ++ks) {
        short8 af, bf0, bf1;
        #pragma unroll
        for (int j = 0; j < 8; ++j) {
            size_t kr = (size_t)(ks * 32 + j);
            af[j]  = bf16r(aptr [kr * LL]);
            bf0[j] = bf16r(b0ptr[kr * CC]);
            bf1[j] = bf16r(b1ptr[kr * CC]);
        }
        acc0 = __builtin_amdgcn_mfma_f32_16x16x32_bf16(af, bf0, acc0, 0, 0, 0);
        acc1 = __builtin_amdgcn_mfma_f32_16x16x32_bf16(af, bf1, acc1, 0, 0, 0);
        if (doBC) {
            short8 bbf;
            #pragma unroll
            for (int j = 0; j < 8; ++j)
                bbf[j] = bf16r(bbptr[(size_t)(ks * 32 + j) * NN]);
            accB = __builtin_amdgcn_mfma_f32_16x16x32_bf16(af, bbf, accB, 0, 0, 0);
        }
    }

    if (doBC) {
        float* dst = (wq >> 1) ? Cm : Bm;
        #pragma unroll
        for (int r = 0; r < 4; ++r) {
            int l = l0 + m0 + quad * 4 + r;
            dst[((size_t)b * LL + l) * NN + m] = accB[r];
        }
    }

    float bd0 = bd[c0 + n0 + m];
    float bd1 = bd[c0 + n0 + 16 + m];
    int cA = c0 + n0 + m;
    int cB = cA + 16;
    #pragma unroll
    for (int r = 0; r < 4; ++r) {
        int l = l0 + m0 + quad * 4 + r;
        float d0 = softplus_f(acc0[r] + bd0);
        float d1 = softplus_f(acc1[r] + bd1);
        float x0 = fbase[(size_t)cA * LL + l];
        float x1 = fbase[(size_t)cB * LL + l];
        du[((size_t)b * LL + l) * CC + cA] = pack_bf2(d0, d0 * x0);
        du[((size_t)b * LL + l) * CC + cB] = pack_bf2(d1, d1 * x1);
    }
}

// ---------------- P1: per-chunk aggregates. P/S now [chunk][n][c] so the
// 32 stores are lane-coalesced (was lane-stride 64B = 16x transaction amp). --
__global__ __launch_bounds__(256) void p1_aggr(
    const uint32_t* __restrict__ du, const float* __restrict__ Bm,
    const float* __restrict__ A_log, float* __restrict__ P, float* __restrict__ S)
{
    int blk = blockIdx.x;
    int cls = blk >> 8;
    int b   = (blk >> 7) & 1;
    int ch  = blk & 127;
    int p0, inner;
    if (cls == 0)      { p0 = 32 * ch;        inner = 1; }
    else if (cls == 1) { p0 = 4095 - 32 * ch; inner = -1; }
    else               { p0 = 63 - (ch >> 1) + 2048 * (ch & 1); inner = 64; }
    int c = threadIdx.x;
    __shared__ float sBm[CLEN * NN];
    for (int i = threadIdx.x; i < CLEN * NN; i += 256) {
        int j = i >> 4, nn = i & 15;
        sBm[i] = Bm[((size_t)b * LL + (p0 + inner * j)) * NN + nn];
    }
    const uint32_t* dub = du + (size_t)b * LL * CC + c;
    uint32_t w[CLEN];
    #pragma unroll
    for (int j = 0; j < CLEN; ++j)
        w[j] = dub[(size_t)(p0 + inner * j) * CC];
    float A2[NN];
    {
        const float4* al = (const float4*)(A_log + c * NN);
        #pragma unroll
        for (int q = 0; q < 4; ++q) {
            float4 v = al[q];
            A2[q*4+0] = -expf(v.x) * LOG2E;
            A2[q*4+1] = -expf(v.y) * LOG2E;
            A2[q*4+2] = -expf(v.z) * LOG2E;
            A2[q*4+3] = -expf(v.w) * LOG2E;
        }
    }
    __syncthreads();
    float Sv[NN] = {};
    float sumd = 0.f;
    #pragma unroll
    for (int j = 0; j < CLEN; ++j) {
        float dx = __uint_as_float(w[j] << 16);
        float uy = __uint_as_float(w[j] & 0xffff0000u);
        sumd += dx;
        float dA[NN];
        #pragma unroll
        for (int nn = 0; nn < NN; ++nn) dA[nn] = __builtin_amdgcn_exp2f(A2[nn] * dx);
        #pragma unroll
        for (int nn = 0; nn < NN; ++nn)
            Sv[nn] = fmaf(dA[nn], Sv[nn], uy * sBm[j * 16 + nn]);
    }
    // [chunk][n][c] layout: lane-consecutive c -> coalesced stores
    size_t base = ((size_t)((cls * 2 + b) * 128 + ch)) * 4096 + c;
    #pragma unroll
    for (int nn = 0; nn < NN; ++nn) {
        P[base + nn * 256] = __builtin_amdgcn_exp2f(A2[nn] * sumd);
        S[base + nn * 256] = Sv[nn];
    }
}

// ---------------- P2: scan chunk aggregates per direction -> Hin ------------
// cn (0..4095) is an opaque row id — [n][c] relabel needs no changes here.
__global__ __launch_bounds__(128) void p2_scan(
    const float* __restrict__ P, const float* __restrict__ S, float* __restrict__ Hin)
{
    int r = blockIdx.x * 128 + threadIdx.x;   // 32768 rows
    int cn = r & 4095;
    int db = r >> 12;
    int d = db >> 1;
    int cls = (d == 1) ? 1 : ((d == 3) ? 2 : 0);
    int b = db & 1;
    const size_t cbase = ((size_t)(cls * 2 + b) * 128) * 4096 + cn;
    const size_t obase = ((size_t)db * 128) * 4096 + cn;
    float h = 0.f;
    for (int g = 0; g < 16; ++g) {
        float pv[8], sv[8];
        #pragma unroll
        for (int i = 0; i < 8; ++i) {
            int ch = g * 8 + i;
            int chm = (d == 2) ? (126 - 2 * (ch >> 1) + (ch & 1)) : ch;
            size_t ix = cbase + (size_t)chm * 4096;
            pv[i] = P[ix];
            sv[i] = S[ix];
        }
        #pragma unroll
        for (int i = 0; i < 8; ++i) {
            Hin[obase + (size_t)(g * 8 + i) * 4096] = h;
            h = fmaf(pv[i], h, sv[i]);
        }
    }
}

// ---------------- P3: replay. Hin reads now [chunk][n][c] -> coalesced. -----
__global__ __launch_bounds__(256) void p3_replay(
    const uint32_t* __restrict__ du, const float* __restrict__ Bm,
    const float* __restrict__ Cm, const float* __restrict__ A_log,
    const float* __restrict__ Hin, float* __restrict__ yA,
    float* __restrict__ yB, float* __restrict__ yC)
{
    int blk = blockIdx.x;
    int sec = blk >> 8;
    int b   = (blk >> 7) & 1;
    int ch  = blk & 127;
    int p0, inner;
    if (sec == 0)      { p0 = 32 * ch;        inner = 1; }
    else if (sec == 1) { p0 = 4095 - 32 * ch; inner = -1; }
    else               { p0 = 63 - (ch >> 1) + 2048 * (ch & 1); inner = 64; }
    int c = threadIdx.x;
    __shared__ float sBm[CLEN * NN];
    __shared__ float sCm[CLEN * NN];
    for (int i = threadIdx.x; i < CLEN * NN; i += 256) {
        int j = i >> 4, nn = i & 15;
        size_t o = ((size_t)b * LL + (p0 + inner * j)) * NN + nn;
        sBm[i] = Bm[o];
        sCm[i] = Cm[o];
    }
    const uint32_t* dub = du + (size_t)b * LL * CC + c;
    uint32_t w[CLEN];
    #pragma unroll
    for (int j = 0; j < CLEN; ++j)
        w[j] = dub[(size_t)(p0 + inner * j) * CC];
    float A2[NN];
    {
        const float4* al = (const float4*)(A_log + c * NN);
        #pragma unroll
        for (int q = 0; q < 4; ++q) {
            float4 v = al[q];
            A2[q*4+0] = -expf(v.x) * LOG2E;
            A2[q*4+1] = -expf(v.y) * LOG2E;
            A2[q*4+2] = -expf(v.z) * LOG2E;
            A2[q*4+3] = -expf(v.w) * LOG2E;
        }
    }

    if (sec == 0) {
        int ch2 = 126 - (ch & ~1) + (ch & 1);
        float h0[NN], h2[NN];
        {
            const float* hp0 = Hin + ((size_t)(0 * 2 + b) * 128 + ch)  * 4096 + c;
            const float* hp2 = Hin + ((size_t)(2 * 2 + b) * 128 + ch2) * 4096 + c;
            #pragma unroll
            for (int nn = 0; nn < NN; ++nn) {
                h0[nn] = hp0[nn * 256];
                h2[nn] = hp2[nn * 256];
            }
        }
        __syncthreads();
        #pragma unroll
        for (int j = 0; j < CLEN; ++j) {
            float dx = __uint_as_float(w[j] << 16);
            float uy = __uint_as_float(w[j] & 0xffff0000u);
            float dA[NN];
            #pragma unroll
            for (int nn = 0; nn < NN; ++nn) dA[nn] = __builtin_amdgcn_exp2f(A2[nn] * dx);
            float y0v = 0.f, y2v = 0.f;
            #pragma unroll
            for (int nn = 0; nn < NN; ++nn) {
                float Bu = uy * sBm[j * 16 + nn];
                float cm = sCm[j * 16 + nn];
                h0[nn] = fmaf(dA[nn], h0[nn], Bu);
                h2[nn] = fmaf(dA[nn], h2[nn], Bu);
                y0v = fmaf(h0[nn], cm, y0v);
                y2v = fmaf(h2[nn], cm, y2v);
            }
            yA[((size_t)b * LL + p0 + j) * CC + c] = 0.25f * (y0v + y2v);
        }
    } else {
        int d = (sec == 1) ? 1 : 3;
        float h[NN];
        {
            const float* hp = Hin + ((size_t)(d * 2 + b) * 128 + ch) * 4096 + c;
            #pragma unroll
            for (int nn = 0; nn < NN; ++nn)
                h[nn] = hp[nn * 256];
        }
        __syncthreads();
        float* yD = (sec == 1) ? yB : yC;
        #pragma unroll
        for (int j = 0; j < CLEN; ++j) {
            float dx = __uint_as_float(w[j] << 16);
            float uy = __uint_as_float(w[j] & 0xffff0000u);
            float dA[NN];
            #pragma unroll
            for (int nn = 0; nn < NN; ++nn) dA[nn] = __builtin_amdgcn_exp2f(A2[nn] * dx);
            float yv = 0.f;
            #pragma unroll
            for (int nn = 0; nn < NN; ++nn) {
                float Bu = uy * sBm[j * 16 + nn];
                h[nn] = fmaf(dA[nn], h[nn], Bu);
                yv = fmaf(h[nn], sCm[j * 16 + nn], yv);
            }
            yD[((size_t)b * LL + p0 + inner * j) * CC + c] = 0.25f * yv;
        }
    }
}

// ---------------- K6: sum 3 y-buffers + x*D, transpose to (B,C,L) -----------
__global__ __launch_bounds__(256) void k6_reduce(
    const float* __restrict__ feat, const float* __restrict__ D,
    const float* __restrict__ yA, const float* __restrict__ yB,
    const float* __restrict__ yC, float* __restrict__ out)
{
    int pt = blockIdx.x & 63;
    int ct = (blockIdx.x >> 6) & 3;
    int b  = blockIdx.x >> 8;
    int p0 = pt * 64, c0 = ct * 64;
    __shared__ float tile[64 * 65];
    {
        int cl = threadIdx.x & 63;
        int pg = threadIdx.x >> 6;
        #pragma unroll
        for (int pp = 0; pp < 16; ++pp) {
            int pl = pp * 4 + pg;
            size_t ix = ((size_t)b * LL + p0 + pl) * CC + c0 + cl;
            tile[cl * 65 + pl] = yA[ix] + yB[ix] + yC[ix];
        }
    }
    __syncthreads();
    {
        int pl = threadIdx.x & 63;
        int cg = threadIdx.x >> 6;
        #pragma unroll
        for (int cc = 0; cc < 16; ++cc) {
            int cloc = cc * 4 + cg;
            int c = c0 + cloc;
            size_t o = ((size_t)b * CC + c) * LL + p0 + pl;
            out[o] = tile[cloc * 65 + pl] + feat[o] * D[c];
        }
    }
}

extern "C" void kernel_launch(void* const* d_in, const int* in_sizes, int n_in,
                              void* d_out, int out_size, void* d_ws, size_t ws_size,
                              hipStream_t stream)
{
    const float* feat  = (const float*)d_in[0];
    const float* A_log = (const float*)d_in[1];
    const float* D     = (const float*)d_in[2];
    const float* Wd    = (const float*)d_in[3];
    const float* bd    = (const float*)d_in[4];
    const float* WB    = (const float*)d_in[5];
    const float* WC    = (const float*)d_in[6];
    float* out = (float*)d_out;

    float* ws  = (float*)d_ws;
    uint32_t* du = (uint32_t*)ws;                         //  2,097,152 u32 (bf16x2)
    float* Bm  = ws  + (size_t)2097152;                   //    131,072
    float* Cm  = Bm  + (size_t)131072;                    //    131,072
    float* P   = Cm  + (size_t)131072;                    //  3,145,728 (3 cls)
    float* S   = P   + (size_t)3145728;                   //  3,145,728
    float* Hin = S   + (size_t)3145728;                   //  4,194,304 (4 dirs)
    float* yA  = Hin + (size_t)4194304;                   //  2,097,152
    float* yB  = yA  + (size_t)2097152;                   //  2,097,152
    float* yC  = yB  + (size_t)2097152;                   //  2,097,152

    k1_mfma<<<1024, 256, 0, stream>>>(feat, Wd, bd, WB, WC, du, Bm, Cm);
    p1_aggr<<<768, 256, 0, stream>>>(du, Bm, A_log, P, S);
    p2_scan<<<256, 128, 0, stream>>>(P, S, Hin);
    p3_replay<<<768, 256, 0, stream>>>(du, Bm, Cm, A_log, Hin, yA, yB, yC);
    k6_reduce<<<512, 256, 0, stream>>>(feat, D, yA, yB, yC, out);
}